// Round 11
// baseline (165.152 us; speedup 1.0000x reference)
//
#include <hip/hip_runtime.h>

// B=2, N=64, D=256, H=8, DK=32.  ROWS = B*N*N = 8192.
#define ROWS 8192
#define DIM  256

typedef short short8 __attribute__((ext_vector_type(8)));
typedef float f4     __attribute__((ext_vector_type(4)));

__device__ __forceinline__ float bf2f(unsigned int u16) {
    union { unsigned int i; float f; } v;
    v.i = (u16 & 0xffffu) << 16;
    return v.f;
}
__device__ __forceinline__ unsigned short f2bf(float f) {
    union { float f; unsigned int u; } v; v.f = f;
    unsigned int r = v.u + 0x7fffu + ((v.u >> 16) & 1u);   // RNE
    return (unsigned short)(r >> 16);
}

// Async global->LDS: 16B per lane, LDS dest = wave-uniform base + lane*16
// (m97/m104). Global src is per-lane.
#define GLD(g, l) __builtin_amdgcn_global_load_lds( \
    (const __attribute__((address_space(1))) void*)(g), \
    (__attribute__((address_space(3))) void*)(l), 16, 0, 0)

// ---------------------------------------------------------------------------
// Merged casts. Blocks [0,2048): x(8192x256 fp32)->xb bf16.
// Blocks [2048,2624): weights -> WT[n][k] bf16 packed.
//   w0..w4 at w*65536 ; W1(256x512)->512x256 @327680 ; W2(512x256)->256x512 @458752
// ---------------------------------------------------------------------------
__global__ __launch_bounds__(256)
void cast_all(const float* __restrict__ x, unsigned short* __restrict__ xb,
              const float* __restrict__ w0, const float* __restrict__ w1,
              const float* __restrict__ w2, const float* __restrict__ w3,
              const float* __restrict__ w4, const float* __restrict__ w5,
              const float* __restrict__ w6, unsigned short* __restrict__ wt)
{
    if (blockIdx.x < 2048) {
        const size_t i = ((size_t)blockIdx.x * 256 + threadIdx.x) * 4;
        float4 v = *(const float4*)(x + i);
        uint2 p;
        p.x = f2bf(v.x) | ((unsigned int)f2bf(v.y) << 16);
        p.y = f2bf(v.z) | ((unsigned int)f2bf(v.w) << 16);
        *(uint2*)(xb + i) = p;
        return;
    }
    __shared__ float t[32][33];
    int id = blockIdx.x - 2048;
    const float* src; int K, N, Ntiles; size_t doff;
    if (id < 320) {
        int w = id >> 6; id &= 63; K = 256; N = 256; Ntiles = 8;
        doff = (size_t)w * 65536;
        src = (w == 0) ? w0 : (w == 1) ? w1 : (w == 2) ? w2 : (w == 3) ? w3 : w4;
    } else if (id < 448) {
        id -= 320; K = 256; N = 512; Ntiles = 16; doff = 327680; src = w5;
    } else {
        id -= 448; K = 512; N = 256; Ntiles = 8;  doff = 458752; src = w6;
    }
    const int tk = id / Ntiles, tn = id % Ntiles;
    const int k0 = tk * 32, n0 = tn * 32;
    const int c = threadIdx.x & 31, r8 = threadIdx.x >> 5;
    for (int rr = r8; rr < 32; rr += 8)
        t[rr][c] = src[(size_t)(k0 + rr) * N + n0 + c];
    __syncthreads();
    for (int rr = r8; rr < 32; rr += 8)
        wt[doff + (size_t)(n0 + rr) * K + k0 + c] = f2bf(t[c][rr]);
}

// ---------------------------------------------------------------------------
// Projection MFMA GEMM with head-major scatter epilogue.
//   wsel 0 (lk): dst[b][h][x=i][a=j][d]   wsel 1 (rk): dst[b][h][a=i][y=j][d]
//   wsel 2 (lv): dst[b][h][x=i][a=j][d]   wsel 3 (rv): dst[b][h][y=j][a=i][d]
// grid (4,64), 1024 thr / 16 waves; full 128KB W[wsel] panel in LDS (R7).
// ---------------------------------------------------------------------------
__global__ __launch_bounds__(1024, 1)
void proj_mfma(const unsigned short* __restrict__ A, const unsigned short* __restrict__ WT,
               unsigned short* __restrict__ projT)
{
    __shared__ unsigned short WL[256 * 256];  // [col][k] bf16, swizzled, 128KB
    const int lane = threadIdx.x & 63, wave = threadIdx.x >> 6;
    const int wsel = blockIdx.x;
    const int col0 = (wave >> 2) * 64;
    const int m0 = blockIdx.y * 128 + (wave & 3) * 32;
    const int lm = lane & 15, lk8 = (lane >> 4) * 8;
    const unsigned short* W = WT + (size_t)wsel * 65536;
    unsigned short* dst = projT + (size_t)wsel * 2097152;

    {   // stage full W panel: 8192 16B chunks, 8 per thread, coalesced reads
        const int tid = threadIdx.x;
        #pragma unroll
        for (int it = 0; it < 8; ++it) {
            const int c = tid + it * 1024;         // chunk id 0..8191
            const int col = c >> 5, ch = c & 31;   // col 0..255, chunk-in-row 0..31
            const uint4 v = *(const uint4*)(W + (size_t)col * 256 + ch * 8);
            *(uint4*)((char*)WL + col * 512 + ((ch ^ (col & 7)) << 4)) = v;
        }
    }
    __syncthreads();

    f4 acc[2][4];
    #pragma unroll
    for (int i = 0; i < 2; ++i)
        #pragma unroll
        for (int j = 0; j < 4; ++j) acc[i][j] = (f4){0.f, 0.f, 0.f, 0.f};

    #pragma unroll 2
    for (int kc = 0; kc < 256; kc += 32) {
        short8 af[2], bf[4];
        #pragma unroll
        for (int i = 0; i < 2; ++i)
            af[i] = *(const short8*)(A + (size_t)(m0 + i * 16 + lm) * 256 + kc + lk8);
        #pragma unroll
        for (int j = 0; j < 4; ++j) {
            const int cl = col0 + j * 16 + lm;
            const int kch = (kc + lk8) >> 3;
            bf[j] = *(const short8*)((char*)WL + cl * 512 + ((kch ^ (cl & 7)) << 4));
        }
        #pragma unroll
        for (int i = 0; i < 2; ++i)
            #pragma unroll
            for (int j = 0; j < 4; ++j)
                acc[i][j] = __builtin_amdgcn_mfma_f32_16x16x32_bf16(af[i], bf[j], acc[i][j], 0, 0, 0);
    }

    const int rbase = (lane >> 4) * 4;
    const int swap = (wsel == 3);
    #pragma unroll
    for (int i = 0; i < 2; ++i)
        #pragma unroll
        for (int j = 0; j < 4; ++j) {
            const int c = col0 + j * 16 + lm;
            const int h = c >> 5, d = c & 31;
            #pragma unroll
            for (int r = 0; r < 4; ++r) {
                const int m = m0 + i * 16 + rbase + r;
                const int b = m >> 12, ii = (m >> 6) & 63, jj = m & 63;
                const int p = swap ? jj : ii;
                const int q = swap ? ii : jj;
                const size_t idx = ((((size_t)b * 8 + h) * 64 + p) * 64 + q) * 32 + d;
                dst[idx] = f2bf(acc[i][j][r]);
            }
        }
}

// ---------------------------------------------------------------------------
// Scores via MFMA: per (b,h), wave w handles a = a0 + w.
//   S_a[x,y] = sum_d lk[x,a,d]*rk[a,y,d] / sqrt(32), stored bf16 as
//   S[b][h][x][a][y].  grid = 256 (b,h,a/4), 256 thr.
// ---------------------------------------------------------------------------
__global__ __launch_bounds__(256)
void scores_mfma(const unsigned short* __restrict__ lkT, const unsigned short* __restrict__ rkT,
                 unsigned short* __restrict__ S)
{
    const int lane = threadIdx.x & 63, wave = threadIdx.x >> 6;
    const int bi = blockIdx.x;
    const int b = bi >> 7, h = (bi >> 4) & 7, a = (bi & 15) * 4 + wave;
    const size_t bh = (size_t)b * 8 + h;
    const int lm = lane & 15, lk8 = (lane >> 4) * 8;

    short8 af[4], bf[4];
    #pragma unroll
    for (int t = 0; t < 4; ++t) {
        af[t] = *(const short8*)(lkT + ((bh * 64 + (t * 16 + lm)) * 64 + a) * 32 + lk8);
        bf[t] = *(const short8*)(rkT + ((bh * 64 + a) * 64 + (t * 16 + lm)) * 32 + lk8);
    }
    const int rbase = (lane >> 4) * 4;
    unsigned short* Sb = S + bh * 262144 + a * 64;   // + x*4096 + y
    #pragma unroll
    for (int mt = 0; mt < 4; ++mt)
        #pragma unroll
        for (int nt = 0; nt < 4; ++nt) {
            f4 acc = (f4){0.f, 0.f, 0.f, 0.f};
            acc = __builtin_amdgcn_mfma_f32_16x16x32_bf16(af[mt], bf[nt], acc, 0, 0, 0);
            #pragma unroll
            for (int r = 0; r < 4; ++r) {
                const int xx = mt * 16 + rbase + r;
                const int yy = nt * 16 + lm;
                Sb[(size_t)xx * 4096 + yy] = f2bf(acc[r] * 0.17677669529663687f);
            }
        }
}

// ---------------------------------------------------------------------------
// Softmax over a + aggregation, block per (b,h,x), 256 thr.  (R6-best,
// frozen: R5 traffic cut and R7 vectorization both regressed/neutral.)
// obuf[(b*64+x)*64+y][h*32+d] bf16.  grid = 1024.
// ---------------------------------------------------------------------------
__global__ __launch_bounds__(256)
void softmax_agg(const unsigned short* __restrict__ S, const unsigned short* __restrict__ lvT,
                 const unsigned short* __restrict__ rvT, unsigned short* __restrict__ obuf)
{
    __shared__ float att[64][64];           // [a][y]
    __shared__ float lvL[64][32];
    __shared__ float smx[4][64], ssm[4][64], invL[64];
    const int bi = blockIdx.x;
    const int b = bi >> 9, h = (bi >> 6) & 7, x = bi & 63;
    const size_t bh = (size_t)b * 8 + h;
    const int tid = threadIdx.x;

    {   // load S[x] slice (8KB bf16, contiguous) -> att f32 ; stage lv -> f32
        const int a = tid >> 2, yo = (tid & 3) * 16;
        const unsigned short* Sp = S + (bh * 64 + x) * 4096 + a * 64 + yo;
        uint4 p0 = *(const uint4*)(Sp);
        uint4 p1 = *(const uint4*)(Sp + 8);
        att[a][yo +  0] = bf2f(p0.x); att[a][yo +  1] = bf2f(p0.x >> 16);
        att[a][yo +  2] = bf2f(p0.y); att[a][yo +  3] = bf2f(p0.y >> 16);
        att[a][yo +  4] = bf2f(p0.z); att[a][yo +  5] = bf2f(p0.z >> 16);
        att[a][yo +  6] = bf2f(p0.w); att[a][yo +  7] = bf2f(p0.w >> 16);
        att[a][yo +  8] = bf2f(p1.x); att[a][yo +  9] = bf2f(p1.x >> 16);
        att[a][yo + 10] = bf2f(p1.y); att[a][yo + 11] = bf2f(p1.y >> 16);
        att[a][yo + 12] = bf2f(p1.z); att[a][yo + 13] = bf2f(p1.z >> 16);
        att[a][yo + 14] = bf2f(p1.w); att[a][yo + 15] = bf2f(p1.w >> 16);
        const int d0 = (tid & 3) * 8;
        uint4 q = *(const uint4*)(lvT + ((bh * 64 + x) * 64 + a) * 32 + d0);
        lvL[a][d0 + 0] = bf2f(q.x); lvL[a][d0 + 1] = bf2f(q.x >> 16);
        lvL[a][d0 + 2] = bf2f(q.y); lvL[a][d0 + 3] = bf2f(q.y >> 16);
        lvL[a][d0 + 4] = bf2f(q.z); lvL[a][d0 + 5] = bf2f(q.z >> 16);
        lvL[a][d0 + 6] = bf2f(q.w); lvL[a][d0 + 7] = bf2f(q.w >> 16);
    }
    __syncthreads();

    {   // per-slice max over a
        const int y = tid & 63, az = tid >> 6;
        float mx = -1e30f;
        for (int a = az; a < 64; a += 4) mx = fmaxf(mx, att[a][y]);
        smx[az][y] = mx;
    }
    __syncthreads();

    {   // exp + partial sums
        const int y = tid & 63, az = tid >> 6;
        const float mx = fmaxf(fmaxf(smx[0][y], smx[1][y]), fmaxf(smx[2][y], smx[3][y]));
        float s = 0.f;
        for (int a = az; a < 64; a += 4) {
            float e = __expf(att[a][y] - mx);
            att[a][y] = e;
            s += e;
        }
        ssm[az][y] = s;
    }
    __syncthreads();
    if (tid < 64)
        invL[tid] = 1.f / (ssm[0][tid] + ssm[1][tid] + ssm[2][tid] + ssm[3][tid]);
    __syncthreads();

    {   // aggregation; thread = (dp = d-pair, yb); y = yb + 16*it
        const int dp = tid & 15, yb = tid >> 4;
        #pragma unroll
        for (int it = 0; it < 4; ++it) {
            const int y = yb + it * 16;
            const unsigned short* rvr = rvT + (bh * 64 + y) * 2048 + dp * 2;
            float a0 = 0.f, a1 = 0.f;
            #pragma unroll 8
            for (int a = 0; a < 64; ++a) {
                unsigned int pk = *(const unsigned int*)(rvr + a * 32);
                float w = att[a][y];
                a0 = fmaf(w * lvL[a][2 * dp],     bf2f(pk),       a0);
                a1 = fmaf(w * lvL[a][2 * dp + 1], bf2f(pk >> 16), a1);
            }
            const float inv = invL[y];
            a0 *= inv; a1 *= inv;
            unsigned int st = f2bf(a0) | ((unsigned int)f2bf(a1) << 16);
            *(unsigned int*)(obuf + (((size_t)b * 64 + x) * 64 + y) * 256 + h * 32 + dp * 2) = st;
        }
    }
}

// ---------------------------------------------------------------------------
// XOR swizzle on 16B chunks (hs/ms tiles).
// ---------------------------------------------------------------------------
__device__ __forceinline__ int swz8(int r, int c, int rl) {
    return r * rl + ((((c >> 3) ^ (r & 7)) << 3) | (c & 7));
}

// ---------------------------------------------------------------------------
// Fused FFN tail, R11: async-staged weights via global_load_lds.
// Model (fits R2/R3/R4/R10): ffn burned ~108K cy/block = ~96 DEPENDENT
// global loads/wave x ~700-900cy (weights bounce L2<->L3 as streaming A/xres
// evicts them) with near-zero MLP (compiler refuses to hoist, R2).
// Fix = m97 pattern: per 32-k chunk, DMA-stage W into an LDS double buffer
// (no register dependency -> whole chunk's loads in flight at once), compute
// from LDS, one barrier per chunk. A-tile staged once (also kills the 8x
// intra-block A redundancy: all waves read identical A fragments in ph1).
// Chunk LDS layout [k-octet][col] (16B entries): fragment ds_read_b128 is
// 256B-contiguous per 16-lane group -> conflict-free. Next-phase chunk-0
// staging overlaps each LN epilogue. Operand values/order identical to R8
// -> bit-identical output.
// ---------------------------------------------------------------------------
__global__ __launch_bounds__(512, 2)
void ffn_fused(const unsigned short* __restrict__ A,
               const unsigned short* __restrict__ WoT,
               const unsigned short* __restrict__ W1T,
               const unsigned short* __restrict__ W2T,
               const float* __restrict__ xres,
               const float* __restrict__ g1, const float* __restrict__ be1,
               const float* __restrict__ b1, const float* __restrict__ b2,
               const float* __restrict__ g2, const float* __restrict__ be2,
               float* __restrict__ out)
{
    __shared__ unsigned short As[32 * 256];     // A tile  [o:32][row:32][8]  16KB
    __shared__ unsigned short hs[32 * 256];     // h  swizzled                16KB
    __shared__ unsigned short ms[32 * 512];     // mid swizzled               32KB
    __shared__ unsigned short wbuf[2 * 16384];  // weight chunk dbuf          64KB
    __shared__ float ps[32][8], pq[32][8];
    const int lane = threadIdx.x & 63, wave = threadIdx.x >> 6;
    const int m0 = blockIdx.x * 32;
    const int lm = lane & 15, lk8 = (lane >> 4) * 8;
    const int og = lane >> 4;                   // k-octet group 0..3
    const int rbase = og * 4;
    const int col0 = wave * 32;                 // phases 1/3: 32 cols/wave
    float hreg[2][2][4];

    // xres residual prefetch into regs (overlaps all staging below)
    float xr[2][2][4];
    #pragma unroll
    for (int i = 0; i < 2; ++i)
        #pragma unroll
        for (int j = 0; j < 2; ++j)
            #pragma unroll
            for (int r = 0; r < 4; ++r)
                xr[i][j][r] = xres[(size_t)(m0 + i * 16 + rbase + r) * 256 + col0 + j * 16 + lm];

    // prologue: stage A tile (16KB) + WoT chunk 0 (16KB)
    #pragma unroll
    for (int s = 0; s < 2; ++s) {
        const int idx = (wave * 2 + s) * 64 + lane;
        GLD(A + (size_t)(m0 + (idx & 31)) * 256 + (idx >> 5) * 8, As + (wave * 2 + s) * 512);
    }
    #pragma unroll
    for (int s = 0; s < 2; ++s) {
        const int idx = (wave * 2 + s) * 64 + lane;
        GLD(WoT + (size_t)(idx & 255) * 256 + (idx >> 8) * 8, wbuf + (wave * 2 + s) * 512);
    }
    __syncthreads();                            // drains vmcnt (compiler-inserted)

    // ---------- phase 1: h = LN(x + A @ WoT^T) ----------
    {
        f4 acc[2][2];
        #pragma unroll
        for (int i = 0; i < 2; ++i)
            #pragma unroll
            for (int j = 0; j < 2; ++j) acc[i][j] = (f4){0.f, 0.f, 0.f, 0.f};
        for (int t = 0; t < 8; ++t) {
            if (t < 7) {                        // stage next chunk
                unsigned short* db = wbuf + ((t + 1) & 1) * 8192;
                const int kcn = (t + 1) * 32;
                #pragma unroll
                for (int s = 0; s < 2; ++s) {
                    const int idx = (wave * 2 + s) * 64 + lane;
                    GLD(WoT + (size_t)(idx & 255) * 256 + kcn + (idx >> 8) * 8, db + (wave * 2 + s) * 512);
                }
            }
            const unsigned short* wb = wbuf + (t & 1) * 8192;
            const int oA = t * 4 + og;
            short8 af[2], bf[2];
            #pragma unroll
            for (int i = 0; i < 2; ++i)
                af[i] = *(const short8*)(As + (oA * 32 + i * 16 + lm) * 8);
            #pragma unroll
            for (int j = 0; j < 2; ++j)
                bf[j] = *(const short8*)(wb + (og * 256 + col0 + j * 16 + lm) * 8);
            #pragma unroll
            for (int i = 0; i < 2; ++i)
                #pragma unroll
                for (int j = 0; j < 2; ++j)
                    acc[i][j] = __builtin_amdgcn_mfma_f32_16x16x32_bf16(af[i], bf[j], acc[i][j], 0, 0, 0);
            __syncthreads();                    // next buf ready, cur consumed
        }
        // stage W1T chunk 0 (32KB) — overlaps the LN epilogue below
        #pragma unroll
        for (int s = 0; s < 4; ++s) {
            const int idx = (wave * 4 + s) * 64 + lane;
            GLD(W1T + (size_t)(idx & 511) * 256 + (idx >> 9) * 8, wbuf + (wave * 4 + s) * 512);
        }
        float v[2][2][4], s1[2][4], q1[2][4];
        #pragma unroll
        for (int i = 0; i < 2; ++i)
            #pragma unroll
            for (int r = 0; r < 4; ++r) { s1[i][r] = 0.f; q1[i][r] = 0.f; }
        #pragma unroll
        for (int i = 0; i < 2; ++i)
            #pragma unroll
            for (int j = 0; j < 2; ++j)
                #pragma unroll
                for (int r = 0; r < 4; ++r) {
                    const float t = acc[i][j][r] + xr[i][j][r];
                    v[i][j][r] = t;
                    s1[i][r] += t;
                    q1[i][r] = fmaf(t, t, q1[i][r]);
                }
        #pragma unroll
        for (int off = 1; off < 16; off <<= 1)
            #pragma unroll
            for (int i = 0; i < 2; ++i)
                #pragma unroll
                for (int r = 0; r < 4; ++r) {
                    s1[i][r] += __shfl_xor(s1[i][r], off);
                    q1[i][r] += __shfl_xor(q1[i][r], off);
                }
        if (lm == 0)
            #pragma unroll
            for (int i = 0; i < 2; ++i)
                #pragma unroll
                for (int r = 0; r < 4; ++r) {
                    ps[i * 16 + rbase + r][wave] = s1[i][r];
                    pq[i * 16 + rbase + r][wave] = q1[i][r];
                }
        __syncthreads();
        #pragma unroll
        for (int i = 0; i < 2; ++i)
            #pragma unroll
            for (int r = 0; r < 4; ++r) {
                const int lr = i * 16 + rbase + r;
                const float Sm = ps[lr][0] + ps[lr][1] + ps[lr][2] + ps[lr][3]
                               + ps[lr][4] + ps[lr][5] + ps[lr][6] + ps[lr][7];
                const float Qm = pq[lr][0] + pq[lr][1] + pq[lr][2] + pq[lr][3]
                               + pq[lr][4] + pq[lr][5] + pq[lr][6] + pq[lr][7];
                const float mu = Sm * (1.f / 256.f);
                const float ri = rsqrtf(Qm * (1.f / 256.f) - mu * mu + 1e-5f);
                #pragma unroll
                for (int j = 0; j < 2; ++j) {
                    const int n = col0 + j * 16 + lm;
                    const unsigned short hb16 = f2bf((v[i][j][r] - mu) * ri * g1[n] + be1[n]);
                    hs[swz8(lr, n, 256)] = hb16;
                    hreg[i][j][r] = bf2f(hb16);
                }
            }
    }
    __syncthreads();

    // ---------- phase 2: mid = relu(h @ W1T^T + b1) ----------
    {
        const int c0 = wave * 64;
        f4 acc2[2][4];
        #pragma unroll
        for (int i = 0; i < 2; ++i)
            #pragma unroll
            for (int j = 0; j < 4; ++j) acc2[i][j] = (f4){0.f, 0.f, 0.f, 0.f};
        for (int t = 0; t < 8; ++t) {
            if (t < 7) {
                unsigned short* db = wbuf + ((t + 1) & 1) * 16384;
                const int kcn = (t + 1) * 32;
                #pragma unroll
                for (int s = 0; s < 4; ++s) {
                    const int idx = (wave * 4 + s) * 64 + lane;
                    GLD(W1T + (size_t)(idx & 511) * 256 + kcn + (idx >> 9) * 8, db + (wave * 4 + s) * 512);
                }
            }
            const unsigned short* wb = wbuf + (t & 1) * 16384;
            const int kc = t * 32;
            short8 af[2], bf[4];
            #pragma unroll
            for (int i = 0; i < 2; ++i)
                af[i] = *(const short8*)(hs + swz8(i * 16 + lm, kc + lk8, 256));
            #pragma unroll
            for (int j = 0; j < 4; ++j)
                bf[j] = *(const short8*)(wb + (og * 512 + c0 + j * 16 + lm) * 8);
            #pragma unroll
            for (int i = 0; i < 2; ++i)
                #pragma unroll
                for (int j = 0; j < 4; ++j)
                    acc2[i][j] = __builtin_amdgcn_mfma_f32_16x16x32_bf16(af[i], bf[j], acc2[i][j], 0, 0, 0);
            __syncthreads();
        }
        // stage W2T chunk 0 — overlaps the ms epilogue
        #pragma unroll
        for (int s = 0; s < 2; ++s) {
            const int idx = (wave * 2 + s) * 64 + lane;
            GLD(W2T + (size_t)(idx & 255) * 512 + (idx >> 8) * 8, wbuf + (wave * 2 + s) * 512);
        }
        #pragma unroll
        for (int i = 0; i < 2; ++i)
            #pragma unroll
            for (int j = 0; j < 4; ++j) {
                const int n = c0 + j * 16 + lm;
                const float bb = b1[n];
                #pragma unroll
                for (int r = 0; r < 4; ++r)
                    ms[swz8(i * 16 + rbase + r, n, 512)] = f2bf(fmaxf(acc2[i][j][r] + bb, 0.f));
            }
    }
    __syncthreads();

    // ---------- phase 3: out = LN(h + mid @ W2T^T + b2) ----------
    {
        f4 acc[2][2];
        #pragma unroll
        for (int i = 0; i < 2; ++i)
            #pragma unroll
            for (int j = 0; j < 2; ++j) acc[i][j] = (f4){0.f, 0.f, 0.f, 0.f};
        for (int t = 0; t < 16; ++t) {
            if (t < 15) {
                unsigned short* db = wbuf + ((t + 1) & 1) * 8192;
                const int kcn = (t + 1) * 32;
                #pragma unroll
                for (int s = 0; s < 2; ++s) {
                    const int idx = (wave * 2 + s) * 64 + lane;
                    GLD(W2T + (size_t)(idx & 255) * 512 + kcn + (idx >> 8) * 8, db + (wave * 2 + s) * 512);
                }
            }
            const unsigned short* wb = wbuf + (t & 1) * 8192;
            const int kc = t * 32;
            short8 af[2], bf[2];
            #pragma unroll
            for (int i = 0; i < 2; ++i)
                af[i] = *(const short8*)(ms + swz8(i * 16 + lm, kc + lk8, 512));
            #pragma unroll
            for (int j = 0; j < 2; ++j)
                bf[j] = *(const short8*)(wb + (og * 256 + col0 + j * 16 + lm) * 8);
            #pragma unroll
            for (int i = 0; i < 2; ++i)
                #pragma unroll
                for (int j = 0; j < 2; ++j)
                    acc[i][j] = __builtin_amdgcn_mfma_f32_16x16x32_bf16(af[i], bf[j], acc[i][j], 0, 0, 0);
            __syncthreads();
        }
        float v[2][2][4], s3[2][4], q3[2][4];
        #pragma unroll
        for (int i = 0; i < 2; ++i)
            #pragma unroll
            for (int r = 0; r < 4; ++r) { s3[i][r] = 0.f; q3[i][r] = 0.f; }
        #pragma unroll
        for (int i = 0; i < 2; ++i)
            #pragma unroll
            for (int j = 0; j < 2; ++j) {
                const int n = col0 + j * 16 + lm;
                const float bb = b2[n];
                #pragma unroll
                for (int r = 0; r < 4; ++r) {
                    const float t = acc[i][j][r] + bb + hreg[i][j][r];
                    v[i][j][r] = t;
                    s3[i][r] += t;
                    q3[i][r] = fmaf(t, t, q3[i][r]);
                }
            }
        #pragma unroll
        for (int off = 1; off < 16; off <<= 1)
            #pragma unroll
            for (int i = 0; i < 2; ++i)
                #pragma unroll
                for (int r = 0; r < 4; ++r) {
                    s3[i][r] += __shfl_xor(s3[i][r], off);
                    q3[i][r] += __shfl_xor(q3[i][r], off);
                }
        if (lm == 0)
            #pragma unroll
            for (int i = 0; i < 2; ++i)
                #pragma unroll
                for (int r = 0; r < 4; ++r) {
                    ps[i * 16 + rbase + r][wave] = s3[i][r];
                    pq[i * 16 + rbase + r][wave] = q3[i][r];
                }
        __syncthreads();
        #pragma unroll
        for (int i = 0; i < 2; ++i)
            #pragma unroll
            for (int r = 0; r < 4; ++r) {
                const int lr = i * 16 + rbase + r;
                const float Sm = ps[lr][0] + ps[lr][1] + ps[lr][2] + ps[lr][3]
                               + ps[lr][4] + ps[lr][5] + ps[lr][6] + ps[lr][7];
                const float Qm = pq[lr][0] + pq[lr][1] + pq[lr][2] + pq[lr][3]
                               + pq[lr][4] + pq[lr][5] + pq[lr][6] + pq[lr][7];
                const float mu = Sm * (1.f / 256.f);
                const float ri = rsqrtf(Qm * (1.f / 256.f) - mu * mu + 1e-5f);
                const int m = m0 + lr;
                #pragma unroll
                for (int j = 0; j < 2; ++j) {
                    const int n = col0 + j * 16 + lm;
                    out[(size_t)m * 256 + n] = (v[i][j][r] - mu) * ri * g2[n] + be2[n];
                }
            }
    }
}

// ---------------------------------------------------------------------------
extern "C" void kernel_launch(void* const* d_in, const int* in_sizes, int n_in,
                              void* d_out, int out_size, void* d_ws, size_t ws_size,
                              hipStream_t stream)
{
    const float* x    = (const float*)d_in[0];
    const float* Wlk  = (const float*)d_in[1];
    const float* Wrk  = (const float*)d_in[2];
    const float* Wlv  = (const float*)d_in[3];
    const float* Wrv  = (const float*)d_in[4];
    const float* Wout = (const float*)d_in[5];
    const float* g1   = (const float*)d_in[6];
    const float* be1  = (const float*)d_in[7];
    const float* W1   = (const float*)d_in[8];
    const float* b1   = (const float*)d_in[9];
    const float* W2   = (const float*)d_in[10];
    const float* b2   = (const float*)d_in[11];
    const float* g2   = (const float*)d_in[12];
    const float* be2  = (const float*)d_in[13];

    char* base = (char*)d_ws;
    const size_t MB = 1ull << 20;
    unsigned short* xb    = (unsigned short*)(base + 0);        // 4MB; reused as obuf
    unsigned short* obufb = (unsigned short*)(base + 0);
    unsigned short* projT = (unsigned short*)(base + 4 * MB);   // lkT,rkT,lvT,rvT 4x4MB
    unsigned short* lkT   = projT;
    unsigned short* rkT   = projT + 2097152;
    unsigned short* lvT   = projT + 2 * 2097152;
    unsigned short* rvT   = projT + 3 * 2097152;
    unsigned short* Sbuf  = (unsigned short*)(base + 32 * MB);  // 8MB bf16 scores
    unsigned short* WT    = (unsigned short*)(base + 40 * MB);  // 1.2MB

    // 1. casts (x -> bf16, weights -> transposed bf16)
    cast_all<<<2624, 256, 0, stream>>>(x, xb, Wlk, Wrk, Wlv, Wrv, Wout, W1, W2, WT);
    // 2. projections + head-major scatter (full W panel LDS-staged, merged cols)
    proj_mfma<<<dim3(4, 64), 1024, 0, stream>>>(xb, WT, projT);
    // 3. scores via MFMA -> S (bf16)
    scores_mfma<<<256, 256, 0, stream>>>(lkT, rkT, Sbuf);
    // 4. softmax + aggregation -> obuf (bf16)
    softmax_agg<<<1024, 256, 0, stream>>>(Sbuf, lvT, rvT, obufb);
    // 5-7 fused: out = LN( h + relu(h@W1+b1)@W2 + b2 ),  h = LN(x + obuf@W_out)
    ffn_fused<<<256, 512, 0, stream>>>(obufb, WT + 262144, WT + 327680, WT + 458752,
                                       x, g1, be1, b1, b2, g2, be2, (float*)d_out);
}

// Round 12
// 156.502 us; speedup vs baseline: 1.0553x; 1.0553x over previous
//
#include <hip/hip_runtime.h>

// B=2, N=64, D=256, H=8, DK=32.  ROWS = B*N*N = 8192.
#define ROWS 8192
#define DIM  256

typedef short short8 __attribute__((ext_vector_type(8)));
typedef float f4     __attribute__((ext_vector_type(4)));

__device__ __forceinline__ float bf2f(unsigned int u16) {
    union { unsigned int i; float f; } v;
    v.i = (u16 & 0xffffu) << 16;
    return v.f;
}
__device__ __forceinline__ unsigned short f2bf(float f) {
    union { float f; unsigned int u; } v; v.f = f;
    unsigned int r = v.u + 0x7fffu + ((v.u >> 16) & 1u);   // RNE
    return (unsigned short)(r >> 16);
}

// ---------------------------------------------------------------------------
// Merged casts. Blocks [0,2048): x(8192x256 fp32)->xb bf16.
// Blocks [2048,2624): weights -> WT[n][k] bf16 packed.
//   w0..w4 at w*65536 ; W1(256x512)->512x256 @327680 ; W2(512x256)->256x512 @458752
// ---------------------------------------------------------------------------
__global__ __launch_bounds__(256)
void cast_all(const float* __restrict__ x, unsigned short* __restrict__ xb,
              const float* __restrict__ w0, const float* __restrict__ w1,
              const float* __restrict__ w2, const float* __restrict__ w3,
              const float* __restrict__ w4, const float* __restrict__ w5,
              const float* __restrict__ w6, unsigned short* __restrict__ wt)
{
    if (blockIdx.x < 2048) {
        const size_t i = ((size_t)blockIdx.x * 256 + threadIdx.x) * 4;
        float4 v = *(const float4*)(x + i);
        uint2 p;
        p.x = f2bf(v.x) | ((unsigned int)f2bf(v.y) << 16);
        p.y = f2bf(v.z) | ((unsigned int)f2bf(v.w) << 16);
        *(uint2*)(xb + i) = p;
        return;
    }
    __shared__ float t[32][33];
    int id = blockIdx.x - 2048;
    const float* src; int K, N, Ntiles; size_t doff;
    if (id < 320) {
        int w = id >> 6; id &= 63; K = 256; N = 256; Ntiles = 8;
        doff = (size_t)w * 65536;
        src = (w == 0) ? w0 : (w == 1) ? w1 : (w == 2) ? w2 : (w == 3) ? w3 : w4;
    } else if (id < 448) {
        id -= 320; K = 256; N = 512; Ntiles = 16; doff = 327680; src = w5;
    } else {
        id -= 448; K = 512; N = 256; Ntiles = 8;  doff = 458752; src = w6;
    }
    const int tk = id / Ntiles, tn = id % Ntiles;
    const int k0 = tk * 32, n0 = tn * 32;
    const int c = threadIdx.x & 31, r8 = threadIdx.x >> 5;
    for (int rr = r8; rr < 32; rr += 8)
        t[rr][c] = src[(size_t)(k0 + rr) * N + n0 + c];
    __syncthreads();
    for (int rr = r8; rr < 32; rr += 8)
        wt[doff + (size_t)(n0 + rr) * K + k0 + c] = f2bf(t[c][rr]);
}

// ---------------------------------------------------------------------------
// Projection MFMA GEMM with head-major scatter epilogue.  (R6-best version:
// grid (16,64), 256 thr, 64-col W strip staged once per block into LDS —
// the ~11us win. R7's full-panel merge was neutral; R11's async staging
// regressed -> locked at R6.)
//   wsel 0 (lk): dst[b][h][x=i][a=j][d]   wsel 1 (rk): dst[b][h][a=i][y=j][d]
//   wsel 2 (lv): dst[b][h][x=i][a=j][d]   wsel 3 (rv): dst[b][h][y=j][a=i][d]
// ---------------------------------------------------------------------------
__global__ __launch_bounds__(256)
void proj_mfma(const unsigned short* __restrict__ A, const unsigned short* __restrict__ WT,
               unsigned short* __restrict__ projT)
{
    __shared__ unsigned short WL[64 * 256];   // [col][k] bf16, swizzled, 32KB
    const int lane = threadIdx.x & 63, wave = threadIdx.x >> 6;
    const int wsel = blockIdx.x >> 2;
    const int col0 = (blockIdx.x & 3) * 64;
    const int m0 = blockIdx.y * 128 + wave * 32;
    const int lm = lane & 15, lk8 = (lane >> 4) * 8;
    const unsigned short* W = WT + (size_t)wsel * 65536 + (size_t)col0 * 256;
    unsigned short* dst = projT + (size_t)wsel * 2097152;

    {   // stage W strip: 2048 16B chunks, 8 per thread, coalesced reads
        const int tid = threadIdx.x;
        #pragma unroll
        for (int it = 0; it < 8; ++it) {
            const int c = tid + it * 256;          // chunk id
            const int col = c >> 5, ch = c & 31;   // col 0..63, chunk-in-row 0..31
            const uint4 v = *(const uint4*)(W + (size_t)col * 256 + ch * 8);
            *(uint4*)((char*)WL + col * 512 + ((ch ^ (col & 7)) << 4)) = v;
        }
    }
    __syncthreads();

    f4 acc[2][4];
    #pragma unroll
    for (int i = 0; i < 2; ++i)
        #pragma unroll
        for (int j = 0; j < 4; ++j) acc[i][j] = (f4){0.f, 0.f, 0.f, 0.f};

    #pragma unroll 2
    for (int kc = 0; kc < 256; kc += 32) {
        short8 af[2], bf[4];
        #pragma unroll
        for (int i = 0; i < 2; ++i)
            af[i] = *(const short8*)(A + (size_t)(m0 + i * 16 + lm) * 256 + kc + lk8);
        #pragma unroll
        for (int j = 0; j < 4; ++j) {
            const int cl = j * 16 + lm;
            const int kch = (kc + lk8) >> 3;
            bf[j] = *(const short8*)((char*)WL + cl * 512 + ((kch ^ (cl & 7)) << 4));
        }
        #pragma unroll
        for (int i = 0; i < 2; ++i)
            #pragma unroll
            for (int j = 0; j < 4; ++j)
                acc[i][j] = __builtin_amdgcn_mfma_f32_16x16x32_bf16(af[i], bf[j], acc[i][j], 0, 0, 0);
    }

    const int rbase = (lane >> 4) * 4;
    const int swap = (wsel == 3);
    #pragma unroll
    for (int i = 0; i < 2; ++i)
        #pragma unroll
        for (int j = 0; j < 4; ++j) {
            const int c = col0 + j * 16 + lm;
            const int h = c >> 5, d = c & 31;
            #pragma unroll
            for (int r = 0; r < 4; ++r) {
                const int m = m0 + i * 16 + rbase + r;
                const int b = m >> 12, ii = (m >> 6) & 63, jj = m & 63;
                const int p = swap ? jj : ii;
                const int q = swap ? ii : jj;
                const size_t idx = ((((size_t)b * 8 + h) * 64 + p) * 64 + q) * 32 + d;
                dst[idx] = f2bf(acc[i][j][r]);
            }
        }
}

// ---------------------------------------------------------------------------
// Scores via MFMA: per (b,h), wave w handles a = a0 + w.
//   S_a[x,y] = sum_d lk[x,a,d]*rk[a,y,d] / sqrt(32), stored bf16 as
//   S[b][h][x][a][y].  grid = 256 (b,h,a/4), 256 thr.
// ---------------------------------------------------------------------------
__global__ __launch_bounds__(256)
void scores_mfma(const unsigned short* __restrict__ lkT, const unsigned short* __restrict__ rkT,
                 unsigned short* __restrict__ S)
{
    const int lane = threadIdx.x & 63, wave = threadIdx.x >> 6;
    const int bi = blockIdx.x;
    const int b = bi >> 7, h = (bi >> 4) & 7, a = (bi & 15) * 4 + wave;
    const size_t bh = (size_t)b * 8 + h;
    const int lm = lane & 15, lk8 = (lane >> 4) * 8;

    short8 af[4], bf[4];
    #pragma unroll
    for (int t = 0; t < 4; ++t) {
        af[t] = *(const short8*)(lkT + ((bh * 64 + (t * 16 + lm)) * 64 + a) * 32 + lk8);
        bf[t] = *(const short8*)(rkT + ((bh * 64 + a) * 64 + (t * 16 + lm)) * 32 + lk8);
    }
    const int rbase = (lane >> 4) * 4;
    unsigned short* Sb = S + bh * 262144 + a * 64;   // + x*4096 + y
    #pragma unroll
    for (int mt = 0; mt < 4; ++mt)
        #pragma unroll
        for (int nt = 0; nt < 4; ++nt) {
            f4 acc = (f4){0.f, 0.f, 0.f, 0.f};
            acc = __builtin_amdgcn_mfma_f32_16x16x32_bf16(af[mt], bf[nt], acc, 0, 0, 0);
            #pragma unroll
            for (int r = 0; r < 4; ++r) {
                const int xx = mt * 16 + rbase + r;
                const int yy = nt * 16 + lm;
                Sb[(size_t)xx * 4096 + yy] = f2bf(acc[r] * 0.17677669529663687f);
            }
        }
}

// ---------------------------------------------------------------------------
// Softmax over a + aggregation, block per (b,h,x), 256 thr.  (R6-best,
// frozen: R5 traffic cut and R7 vectorization both regressed/neutral —
// this kernel is latency-structured; its 4 independent y-passes give the
// MLP the hardware can actually use.)
// obuf[(b*64+x)*64+y][h*32+d] bf16.  grid = 1024.
// ---------------------------------------------------------------------------
__global__ __launch_bounds__(256)
void softmax_agg(const unsigned short* __restrict__ S, const unsigned short* __restrict__ lvT,
                 const unsigned short* __restrict__ rvT, unsigned short* __restrict__ obuf)
{
    __shared__ float att[64][64];           // [a][y]
    __shared__ float lvL[64][32];
    __shared__ float smx[4][64], ssm[4][64], invL[64];
    const int bi = blockIdx.x;
    const int b = bi >> 9, h = (bi >> 6) & 7, x = bi & 63;
    const size_t bh = (size_t)b * 8 + h;
    const int tid = threadIdx.x;

    {   // load S[x] slice (8KB bf16, contiguous) -> att f32 ; stage lv -> f32
        const int a = tid >> 2, yo = (tid & 3) * 16;
        const unsigned short* Sp = S + (bh * 64 + x) * 4096 + a * 64 + yo;
        uint4 p0 = *(const uint4*)(Sp);
        uint4 p1 = *(const uint4*)(Sp + 8);
        att[a][yo +  0] = bf2f(p0.x); att[a][yo +  1] = bf2f(p0.x >> 16);
        att[a][yo +  2] = bf2f(p0.y); att[a][yo +  3] = bf2f(p0.y >> 16);
        att[a][yo +  4] = bf2f(p0.z); att[a][yo +  5] = bf2f(p0.z >> 16);
        att[a][yo +  6] = bf2f(p0.w); att[a][yo +  7] = bf2f(p0.w >> 16);
        att[a][yo +  8] = bf2f(p1.x); att[a][yo +  9] = bf2f(p1.x >> 16);
        att[a][yo + 10] = bf2f(p1.y); att[a][yo + 11] = bf2f(p1.y >> 16);
        att[a][yo + 12] = bf2f(p1.z); att[a][yo + 13] = bf2f(p1.z >> 16);
        att[a][yo + 14] = bf2f(p1.w); att[a][yo + 15] = bf2f(p1.w >> 16);
        const int d0 = (tid & 3) * 8;
        uint4 q = *(const uint4*)(lvT + ((bh * 64 + x) * 64 + a) * 32 + d0);
        lvL[a][d0 + 0] = bf2f(q.x); lvL[a][d0 + 1] = bf2f(q.x >> 16);
        lvL[a][d0 + 2] = bf2f(q.y); lvL[a][d0 + 3] = bf2f(q.y >> 16);
        lvL[a][d0 + 4] = bf2f(q.z); lvL[a][d0 + 5] = bf2f(q.z >> 16);
        lvL[a][d0 + 6] = bf2f(q.w); lvL[a][d0 + 7] = bf2f(q.w >> 16);
    }
    __syncthreads();

    {   // per-slice max over a
        const int y = tid & 63, az = tid >> 6;
        float mx = -1e30f;
        for (int a = az; a < 64; a += 4) mx = fmaxf(mx, att[a][y]);
        smx[az][y] = mx;
    }
    __syncthreads();

    {   // exp + partial sums
        const int y = tid & 63, az = tid >> 6;
        const float mx = fmaxf(fmaxf(smx[0][y], smx[1][y]), fmaxf(smx[2][y], smx[3][y]));
        float s = 0.f;
        for (int a = az; a < 64; a += 4) {
            float e = __expf(att[a][y] - mx);
            att[a][y] = e;
            s += e;
        }
        ssm[az][y] = s;
    }
    __syncthreads();
    if (tid < 64)
        invL[tid] = 1.f / (ssm[0][tid] + ssm[1][tid] + ssm[2][tid] + ssm[3][tid]);
    __syncthreads();

    {   // aggregation; thread = (dp = d-pair, yb); y = yb + 16*it
        const int dp = tid & 15, yb = tid >> 4;
        #pragma unroll
        for (int it = 0; it < 4; ++it) {
            const int y = yb + it * 16;
            const unsigned short* rvr = rvT + (bh * 64 + y) * 2048 + dp * 2;
            float a0 = 0.f, a1 = 0.f;
            #pragma unroll 8
            for (int a = 0; a < 64; ++a) {
                unsigned int pk = *(const unsigned int*)(rvr + a * 32);
                float w = att[a][y];
                a0 = fmaf(w * lvL[a][2 * dp],     bf2f(pk),       a0);
                a1 = fmaf(w * lvL[a][2 * dp + 1], bf2f(pk >> 16), a1);
            }
            const float inv = invL[y];
            a0 *= inv; a1 *= inv;
            unsigned int st = f2bf(a0) | ((unsigned int)f2bf(a1) << 16);
            *(unsigned int*)(obuf + (((size_t)b * 64 + x) * 64 + y) * 256 + h * 32 + dp * 2) = st;
        }
    }
}

// ---------------------------------------------------------------------------
// XOR swizzle on 16B chunks: row stride of both LDS tiles is a multiple of
// 128B, so unswizzled column reads (16 lanes, same col, rows 0..15) would be
// a 16-way bank conflict. chunk' = chunk ^ (row & 7) spreads them over 8
// chunk slots (2-way = free, m136).
// ---------------------------------------------------------------------------
__device__ __forceinline__ int swz8(int r, int c, int rl) {
    return r * rl + ((((c >> 3) ^ (r & 7)) << 3) | (c & 7));
}

// ---------------------------------------------------------------------------
// Fused FFN tail: one block per 32 output rows, 512 thr / 8 waves (grid 256).
// R4-best version, locked. Ledger: ILP lift (R2) null, TLP 2x (R3) null,
// BM16->32 (R4) -13.5us, K-rotation (R10) null, async global_load_lds (R11)
// REGRESSED ~8us (per-chunk __syncthreads drains vmcnt(0) -> prefetch never
// overlaps, and chunked staging capped MLP below the compiler's unrolled
// plain-load schedule). Going past this needs raw s_barrier + counted
// vmcnt(N) (8-phase template) — out of scope for this polish session.
// ---------------------------------------------------------------------------
__global__ __launch_bounds__(512, 2)
void ffn_fused(const unsigned short* __restrict__ A,
               const unsigned short* __restrict__ WoT,
               const unsigned short* __restrict__ W1T,
               const unsigned short* __restrict__ W2T,
               const float* __restrict__ xres,
               const float* __restrict__ g1, const float* __restrict__ be1,
               const float* __restrict__ b1, const float* __restrict__ b2,
               const float* __restrict__ g2, const float* __restrict__ be2,
               float* __restrict__ out)
{
    __shared__ unsigned short hs[32 * 256];   // h   32x256 bf16, swizzled (16KB)
    __shared__ unsigned short ms[32 * 512];   // mid 32x512 bf16, swizzled (32KB)
    __shared__ float ps[32][8], pq[32][8];
    const int lane = threadIdx.x & 63, wave = threadIdx.x >> 6;
    const int m0 = blockIdx.x * 32;
    const int lm = lane & 15, lk8 = (lane >> 4) * 8;
    const int rbase = (lane >> 4) * 4;
    const int col0 = wave * 32;               // phases 1/3: 32 cols per wave
    float hreg[2][2][4];                      // [row-tile][col-tile][r]

    // ---------- phase 1: h = LN(x + A @ WoT^T) ----------
    {
        f4 acc[2][2];
        #pragma unroll
        for (int i = 0; i < 2; ++i)
            #pragma unroll
            for (int j = 0; j < 2; ++j) acc[i][j] = (f4){0.f, 0.f, 0.f, 0.f};
        #pragma unroll
        for (int kc = 0; kc < 256; kc += 32) {
            short8 af[2], bf[2];
            #pragma unroll
            for (int i = 0; i < 2; ++i)
                af[i] = *(const short8*)(A + (size_t)(m0 + i * 16 + lm) * 256 + kc + lk8);
            #pragma unroll
            for (int j = 0; j < 2; ++j)
                bf[j] = *(const short8*)(WoT + (size_t)(col0 + j * 16 + lm) * 256 + kc + lk8);
            #pragma unroll
            for (int i = 0; i < 2; ++i)
                #pragma unroll
                for (int j = 0; j < 2; ++j)
                    acc[i][j] = __builtin_amdgcn_mfma_f32_16x16x32_bf16(af[i], bf[j], acc[i][j], 0, 0, 0);
        }
        float v[2][2][4], s[2][4], q[2][4];
        #pragma unroll
        for (int i = 0; i < 2; ++i)
            #pragma unroll
            for (int r = 0; r < 4; ++r) { s[i][r] = 0.f; q[i][r] = 0.f; }
        #pragma unroll
        for (int i = 0; i < 2; ++i)
            #pragma unroll
            for (int j = 0; j < 2; ++j) {
                const int n = col0 + j * 16 + lm;
                #pragma unroll
                for (int r = 0; r < 4; ++r) {
                    const float t = acc[i][j][r] + xres[(size_t)(m0 + i * 16 + rbase + r) * 256 + n];
                    v[i][j][r] = t;
                    s[i][r] += t;
                    q[i][r] = fmaf(t, t, q[i][r]);
                }
            }
        #pragma unroll
        for (int off = 1; off < 16; off <<= 1)
            #pragma unroll
            for (int i = 0; i < 2; ++i)
                #pragma unroll
                for (int r = 0; r < 4; ++r) {
                    s[i][r] += __shfl_xor(s[i][r], off);
                    q[i][r] += __shfl_xor(q[i][r], off);
                }
        if (lm == 0)
            #pragma unroll
            for (int i = 0; i < 2; ++i)
                #pragma unroll
                for (int r = 0; r < 4; ++r) {
                    ps[i * 16 + rbase + r][wave] = s[i][r];
                    pq[i * 16 + rbase + r][wave] = q[i][r];
                }
        __syncthreads();
        #pragma unroll
        for (int i = 0; i < 2; ++i)
            #pragma unroll
            for (int r = 0; r < 4; ++r) {
                const int lr = i * 16 + rbase + r;
                const float Sm = ps[lr][0] + ps[lr][1] + ps[lr][2] + ps[lr][3]
                               + ps[lr][4] + ps[lr][5] + ps[lr][6] + ps[lr][7];
                const float Qm = pq[lr][0] + pq[lr][1] + pq[lr][2] + pq[lr][3]
                               + pq[lr][4] + pq[lr][5] + pq[lr][6] + pq[lr][7];
                const float mu = Sm * (1.f / 256.f);
                const float ri = rsqrtf(Qm * (1.f / 256.f) - mu * mu + 1e-5f);
                #pragma unroll
                for (int j = 0; j < 2; ++j) {
                    const int n = col0 + j * 16 + lm;
                    const unsigned short hb16 = f2bf((v[i][j][r] - mu) * ri * g1[n] + be1[n]);
                    hs[swz8(lr, n, 256)] = hb16;
                    hreg[i][j][r] = bf2f(hb16);
                }
            }
    }
    __syncthreads();

    // ---------- phase 2: mid = relu(h @ W1T^T + b1) ----------
    {
        const int c0 = wave * 64;
        f4 acc2[2][4];
        #pragma unroll
        for (int i = 0; i < 2; ++i)
            #pragma unroll
            for (int j = 0; j < 4; ++j) acc2[i][j] = (f4){0.f, 0.f, 0.f, 0.f};
        #pragma unroll
        for (int kc = 0; kc < 256; kc += 32) {
            short8 af[2], bf[4];
            #pragma unroll
            for (int i = 0; i < 2; ++i)
                af[i] = *(const short8*)(hs + swz8(i * 16 + lm, kc + lk8, 256));
            #pragma unroll
            for (int j = 0; j < 4; ++j)
                bf[j] = *(const short8*)(W1T + (size_t)(c0 + j * 16 + lm) * 256 + kc + lk8);
            #pragma unroll
            for (int i = 0; i < 2; ++i)
                #pragma unroll
                for (int j = 0; j < 4; ++j)
                    acc2[i][j] = __builtin_amdgcn_mfma_f32_16x16x32_bf16(af[i], bf[j], acc2[i][j], 0, 0, 0);
        }
        #pragma unroll
        for (int i = 0; i < 2; ++i)
            #pragma unroll
            for (int j = 0; j < 4; ++j) {
                const int n = c0 + j * 16 + lm;
                const float bb = b1[n];
                #pragma unroll
                for (int r = 0; r < 4; ++r)
                    ms[swz8(i * 16 + rbase + r, n, 512)] = f2bf(fmaxf(acc2[i][j][r] + bb, 0.f));
            }
    }
    __syncthreads();

    // ---------- phase 3: out = LN(h + mid @ W2T^T + b2) ----------
    {
        f4 acc[2][2];
        #pragma unroll
        for (int i = 0; i < 2; ++i)
            #pragma unroll
            for (int j = 0; j < 2; ++j) acc[i][j] = (f4){0.f, 0.f, 0.f, 0.f};
        #pragma unroll
        for (int kc = 0; kc < 512; kc += 32) {
            short8 af[2], bf[2];
            #pragma unroll
            for (int i = 0; i < 2; ++i)
                af[i] = *(const short8*)(ms + swz8(i * 16 + lm, kc + lk8, 512));
            #pragma unroll
            for (int j = 0; j < 2; ++j)
                bf[j] = *(const short8*)(W2T + (size_t)(col0 + j * 16 + lm) * 512 + kc + lk8);
            #pragma unroll
            for (int i = 0; i < 2; ++i)
                #pragma unroll
                for (int j = 0; j < 2; ++j)
                    acc[i][j] = __builtin_amdgcn_mfma_f32_16x16x32_bf16(af[i], bf[j], acc[i][j], 0, 0, 0);
        }
        float v[2][2][4], s[2][4], q[2][4];
        #pragma unroll
        for (int i = 0; i < 2; ++i)
            #pragma unroll
            for (int r = 0; r < 4; ++r) { s[i][r] = 0.f; q[i][r] = 0.f; }
        #pragma unroll
        for (int i = 0; i < 2; ++i)
            #pragma unroll
            for (int j = 0; j < 2; ++j) {
                const int n = col0 + j * 16 + lm;
                const float bb = b2[n];
                #pragma unroll
                for (int r = 0; r < 4; ++r) {
                    const float t = acc[i][j][r] + bb + hreg[i][j][r];
                    v[i][j][r] = t;
                    s[i][r] += t;
                    q[i][r] = fmaf(t, t, q[i][r]);
                }
            }
        #pragma unroll
        for (int off = 1; off < 16; off <<= 1)
            #pragma unroll
            for (int i = 0; i < 2; ++i)
                #pragma unroll
                for (int r = 0; r < 4; ++r) {
                    s[i][r] += __shfl_xor(s[i][r], off);
                    q[i][r] += __shfl_xor(q[i][r], off);
                }
        if (lm == 0)
            #pragma unroll
            for (int i = 0; i < 2; ++i)
                #pragma unroll
                for (int r = 0; r < 4; ++r) {
                    ps[i * 16 + rbase + r][wave] = s[i][r];
                    pq[i * 16 + rbase + r][wave] = q[i][r];
                }
        __syncthreads();
        #pragma unroll
        for (int i = 0; i < 2; ++i)
            #pragma unroll
            for (int r = 0; r < 4; ++r) {
                const int lr = i * 16 + rbase + r;
                const float Sm = ps[lr][0] + ps[lr][1] + ps[lr][2] + ps[lr][3]
                               + ps[lr][4] + ps[lr][5] + ps[lr][6] + ps[lr][7];
                const float Qm = pq[lr][0] + pq[lr][1] + pq[lr][2] + pq[lr][3]
                               + pq[lr][4] + pq[lr][5] + pq[lr][6] + pq[lr][7];
                const float mu = Sm * (1.f / 256.f);
                const float ri = rsqrtf(Qm * (1.f / 256.f) - mu * mu + 1e-5f);
                const int m = m0 + lr;
                #pragma unroll
                for (int j = 0; j < 2; ++j) {
                    const int n = col0 + j * 16 + lm;
                    out[(size_t)m * 256 + n] = (v[i][j][r] - mu) * ri * g2[n] + be2[n];
                }
            }
    }
}

// ---------------------------------------------------------------------------
extern "C" void kernel_launch(void* const* d_in, const int* in_sizes, int n_in,
                              void* d_out, int out_size, void* d_ws, size_t ws_size,
                              hipStream_t stream)
{
    const float* x    = (const float*)d_in[0];
    const float* Wlk  = (const float*)d_in[1];
    const float* Wrk  = (const float*)d_in[2];
    const float* Wlv  = (const float*)d_in[3];
    const float* Wrv  = (const float*)d_in[4];
    const float* Wout = (const float*)d_in[5];
    const float* g1   = (const float*)d_in[6];
    const float* be1  = (const float*)d_in[7];
    const float* W1   = (const float*)d_in[8];
    const float* b1   = (const float*)d_in[9];
    const float* W2   = (const float*)d_in[10];
    const float* b2   = (const float*)d_in[11];
    const float* g2   = (const float*)d_in[12];
    const float* be2  = (const float*)d_in[13];

    char* base = (char*)d_ws;
    const size_t MB = 1ull << 20;
    unsigned short* xb    = (unsigned short*)(base + 0);        // 4MB; reused as obuf
    unsigned short* obufb = (unsigned short*)(base + 0);
    unsigned short* projT = (unsigned short*)(base + 4 * MB);   // lkT,rkT,lvT,rvT 4x4MB
    unsigned short* lkT   = projT;
    unsigned short* rkT   = projT + 2097152;
    unsigned short* lvT   = projT + 2 * 2097152;
    unsigned short* rvT   = projT + 3 * 2097152;
    unsigned short* Sbuf  = (unsigned short*)(base + 32 * MB);  // 8MB bf16 scores
    unsigned short* WT    = (unsigned short*)(base + 40 * MB);  // 1.2MB

    // 1. casts (x -> bf16, weights -> transposed bf16)
    cast_all<<<2624, 256, 0, stream>>>(x, xb, Wlk, Wrk, Wlv, Wrv, Wout, W1, W2, WT);
    // 2. projections + head-major scatter (W strip LDS-staged)
    proj_mfma<<<dim3(16, 64), 256, 0, stream>>>(xb, WT, projT);
    // 3. scores via MFMA -> S (bf16)
    scores_mfma<<<256, 256, 0, stream>>>(lkT, rkT, Sbuf);
    // 4. softmax + aggregation -> obuf (bf16)
    softmax_agg<<<1024, 256, 0, stream>>>(Sbuf, lvT, rvT, obufb);
    // 5-7 fused: out = LN( h + relu(h@W1+b1)@W2 + b2 ),  h = LN(x + obuf@W_out)
    ffn_fused<<<256, 512, 0, stream>>>(obufb, WT + 262144, WT + 327680, WT + 458752,
                                       x, g1, be1, b1, b2, g2, be2, (float*)d_out);
}

// Round 14
// 155.826 us; speedup vs baseline: 1.0599x; 1.0043x over previous
//
#include <hip/hip_runtime.h>

// B=2, N=64, D=256, H=8, DK=32.  ROWS = B*N*N = 8192.
#define ROWS 8192
#define DIM  256

typedef short short8 __attribute__((ext_vector_type(8)));
typedef float f4     __attribute__((ext_vector_type(4)));

__device__ __forceinline__ float bf2f(unsigned int u16) {
    union { unsigned int i; float f; } v;
    v.i = (u16 & 0xffffu) << 16;
    return v.f;
}
__device__ __forceinline__ unsigned short f2bf(float f) {
    union { float f; unsigned int u; } v; v.f = f;
    unsigned int r = v.u + 0x7fffu + ((v.u >> 16) & 1u);   // RNE
    return (unsigned short)(r >> 16);
}

// ---------------------------------------------------------------------------
// Merged casts. Blocks [0,2048): x(8192x256 fp32)->xb bf16.
// Blocks [2048,2624): weights -> WT[n][k] bf16 packed.
//   w0..w4 at w*65536 ; W1(256x512)->512x256 @327680 ; W2(512x256)->256x512 @458752
// ---------------------------------------------------------------------------
__global__ __launch_bounds__(256)
void cast_all(const float* __restrict__ x, unsigned short* __restrict__ xb,
              const float* __restrict__ w0, const float* __restrict__ w1,
              const float* __restrict__ w2, const float* __restrict__ w3,
              const float* __restrict__ w4, const float* __restrict__ w5,
              const float* __restrict__ w6, unsigned short* __restrict__ wt)
{
    if (blockIdx.x < 2048) {
        const size_t i = ((size_t)blockIdx.x * 256 + threadIdx.x) * 4;
        float4 v = *(const float4*)(x + i);
        uint2 p;
        p.x = f2bf(v.x) | ((unsigned int)f2bf(v.y) << 16);
        p.y = f2bf(v.z) | ((unsigned int)f2bf(v.w) << 16);
        *(uint2*)(xb + i) = p;
        return;
    }
    __shared__ float t[32][33];
    int id = blockIdx.x - 2048;
    const float* src; int K, N, Ntiles; size_t doff;
    if (id < 320) {
        int w = id >> 6; id &= 63; K = 256; N = 256; Ntiles = 8;
        doff = (size_t)w * 65536;
        src = (w == 0) ? w0 : (w == 1) ? w1 : (w == 2) ? w2 : (w == 3) ? w3 : w4;
    } else if (id < 448) {
        id -= 320; K = 256; N = 512; Ntiles = 16; doff = 327680; src = w5;
    } else {
        id -= 448; K = 512; N = 256; Ntiles = 8;  doff = 458752; src = w6;
    }
    const int tk = id / Ntiles, tn = id % Ntiles;
    const int k0 = tk * 32, n0 = tn * 32;
    const int c = threadIdx.x & 31, r8 = threadIdx.x >> 5;
    for (int rr = r8; rr < 32; rr += 8)
        t[rr][c] = src[(size_t)(k0 + rr) * N + n0 + c];
    __syncthreads();
    for (int rr = r8; rr < 32; rr += 8)
        wt[doff + (size_t)(n0 + rr) * K + k0 + c] = f2bf(t[c][rr]);
}

// ---------------------------------------------------------------------------
// Projection MFMA GEMM with head-major scatter epilogue.  (R6-best, frozen.)
//   wsel 0 (lk): dst[b][h][x=i][a=j][d]   wsel 1 (rk): dst[b][h][a=i][y=j][d]
//   wsel 2 (lv): dst[b][h][x=i][a=j][d]   wsel 3 (rv): dst[b][h][y=j][a=i][d]
// ---------------------------------------------------------------------------
__global__ __launch_bounds__(256)
void proj_mfma(const unsigned short* __restrict__ A, const unsigned short* __restrict__ WT,
               unsigned short* __restrict__ projT)
{
    __shared__ unsigned short WL[64 * 256];   // [col][k] bf16, swizzled, 32KB
    const int lane = threadIdx.x & 63, wave = threadIdx.x >> 6;
    const int wsel = blockIdx.x >> 2;
    const int col0 = (blockIdx.x & 3) * 64;
    const int m0 = blockIdx.y * 128 + wave * 32;
    const int lm = lane & 15, lk8 = (lane >> 4) * 8;
    const unsigned short* W = WT + (size_t)wsel * 65536 + (size_t)col0 * 256;
    unsigned short* dst = projT + (size_t)wsel * 2097152;

    {   // stage W strip: 2048 16B chunks, 8 per thread, coalesced reads
        const int tid = threadIdx.x;
        #pragma unroll
        for (int it = 0; it < 8; ++it) {
            const int c = tid + it * 256;          // chunk id
            const int col = c >> 5, ch = c & 31;   // col 0..63, chunk-in-row 0..31
            const uint4 v = *(const uint4*)(W + (size_t)col * 256 + ch * 8);
            *(uint4*)((char*)WL + col * 512 + ((ch ^ (col & 7)) << 4)) = v;
        }
    }
    __syncthreads();

    f4 acc[2][4];
    #pragma unroll
    for (int i = 0; i < 2; ++i)
        #pragma unroll
        for (int j = 0; j < 4; ++j) acc[i][j] = (f4){0.f, 0.f, 0.f, 0.f};

    #pragma unroll 2
    for (int kc = 0; kc < 256; kc += 32) {
        short8 af[2], bf[4];
        #pragma unroll
        for (int i = 0; i < 2; ++i)
            af[i] = *(const short8*)(A + (size_t)(m0 + i * 16 + lm) * 256 + kc + lk8);
        #pragma unroll
        for (int j = 0; j < 4; ++j) {
            const int cl = j * 16 + lm;
            const int kch = (kc + lk8) >> 3;
            bf[j] = *(const short8*)((char*)WL + cl * 512 + ((kch ^ (cl & 7)) << 4));
        }
        #pragma unroll
        for (int i = 0; i < 2; ++i)
            #pragma unroll
            for (int j = 0; j < 4; ++j)
                acc[i][j] = __builtin_amdgcn_mfma_f32_16x16x32_bf16(af[i], bf[j], acc[i][j], 0, 0, 0);
    }

    const int rbase = (lane >> 4) * 4;
    const int swap = (wsel == 3);
    #pragma unroll
    for (int i = 0; i < 2; ++i)
        #pragma unroll
        for (int j = 0; j < 4; ++j) {
            const int c = col0 + j * 16 + lm;
            const int h = c >> 5, d = c & 31;
            #pragma unroll
            for (int r = 0; r < 4; ++r) {
                const int m = m0 + i * 16 + rbase + r;
                const int b = m >> 12, ii = (m >> 6) & 63, jj = m & 63;
                const int p = swap ? jj : ii;
                const int q = swap ? ii : jj;
                const size_t idx = ((((size_t)b * 8 + h) * 64 + p) * 64 + q) * 32 + d;
                dst[idx] = f2bf(acc[i][j][r]);
            }
        }
}

// ---------------------------------------------------------------------------
// Scores via MFMA: per (b,h), wave w handles a = a0 + w.  (frozen)
// ---------------------------------------------------------------------------
__global__ __launch_bounds__(256)
void scores_mfma(const unsigned short* __restrict__ lkT, const unsigned short* __restrict__ rkT,
                 unsigned short* __restrict__ S)
{
    const int lane = threadIdx.x & 63, wave = threadIdx.x >> 6;
    const int bi = blockIdx.x;
    const int b = bi >> 7, h = (bi >> 4) & 7, a = (bi & 15) * 4 + wave;
    const size_t bh = (size_t)b * 8 + h;
    const int lm = lane & 15, lk8 = (lane >> 4) * 8;

    short8 af[4], bf[4];
    #pragma unroll
    for (int t = 0; t < 4; ++t) {
        af[t] = *(const short8*)(lkT + ((bh * 64 + (t * 16 + lm)) * 64 + a) * 32 + lk8);
        bf[t] = *(const short8*)(rkT + ((bh * 64 + a) * 64 + (t * 16 + lm)) * 32 + lk8);
    }
    const int rbase = (lane >> 4) * 4;
    unsigned short* Sb = S + bh * 262144 + a * 64;   // + x*4096 + y
    #pragma unroll
    for (int mt = 0; mt < 4; ++mt)
        #pragma unroll
        for (int nt = 0; nt < 4; ++nt) {
            f4 acc = (f4){0.f, 0.f, 0.f, 0.f};
            acc = __builtin_amdgcn_mfma_f32_16x16x32_bf16(af[mt], bf[nt], acc, 0, 0, 0);
            #pragma unroll
            for (int r = 0; r < 4; ++r) {
                const int xx = mt * 16 + rbase + r;
                const int yy = nt * 16 + lm;
                Sb[(size_t)xx * 4096 + yy] = f2bf(acc[r] * 0.17677669529663687f);
            }
        }
}

// ---------------------------------------------------------------------------
// Softmax over a + aggregation, block per (b,h,x), 256 thr.  (R6-best, frozen)
// ---------------------------------------------------------------------------
__global__ __launch_bounds__(256)
void softmax_agg(const unsigned short* __restrict__ S, const unsigned short* __restrict__ lvT,
                 const unsigned short* __restrict__ rvT, unsigned short* __restrict__ obuf)
{
    __shared__ float att[64][64];           // [a][y]
    __shared__ float lvL[64][32];
    __shared__ float smx[4][64], ssm[4][64], invL[64];
    const int bi = blockIdx.x;
    const int b = bi >> 9, h = (bi >> 6) & 7, x = bi & 63;
    const size_t bh = (size_t)b * 8 + h;
    const int tid = threadIdx.x;

    {   // load S[x] slice (8KB bf16, contiguous) -> att f32 ; stage lv -> f32
        const int a = tid >> 2, yo = (tid & 3) * 16;
        const unsigned short* Sp = S + (bh * 64 + x) * 4096 + a * 64 + yo;
        uint4 p0 = *(const uint4*)(Sp);
        uint4 p1 = *(const uint4*)(Sp + 8);
        att[a][yo +  0] = bf2f(p0.x); att[a][yo +  1] = bf2f(p0.x >> 16);
        att[a][yo +  2] = bf2f(p0.y); att[a][yo +  3] = bf2f(p0.y >> 16);
        att[a][yo +  4] = bf2f(p0.z); att[a][yo +  5] = bf2f(p0.z >> 16);
        att[a][yo +  6] = bf2f(p0.w); att[a][yo +  7] = bf2f(p0.w >> 16);
        att[a][yo +  8] = bf2f(p1.x); att[a][yo +  9] = bf2f(p1.x >> 16);
        att[a][yo + 10] = bf2f(p1.y); att[a][yo + 11] = bf2f(p1.y >> 16);
        att[a][yo + 12] = bf2f(p1.z); att[a][yo + 13] = bf2f(p1.z >> 16);
        att[a][yo + 14] = bf2f(p1.w); att[a][yo + 15] = bf2f(p1.w >> 16);
        const int d0 = (tid & 3) * 8;
        uint4 q = *(const uint4*)(lvT + ((bh * 64 + x) * 64 + a) * 32 + d0);
        lvL[a][d0 + 0] = bf2f(q.x); lvL[a][d0 + 1] = bf2f(q.x >> 16);
        lvL[a][d0 + 2] = bf2f(q.y); lvL[a][d0 + 3] = bf2f(q.y >> 16);
        lvL[a][d0 + 4] = bf2f(q.z); lvL[a][d0 + 5] = bf2f(q.z >> 16);
        lvL[a][d0 + 6] = bf2f(q.w); lvL[a][d0 + 7] = bf2f(q.w >> 16);
    }
    __syncthreads();

    {   // per-slice max over a
        const int y = tid & 63, az = tid >> 6;
        float mx = -1e30f;
        for (int a = az; a < 64; a += 4) mx = fmaxf(mx, att[a][y]);
        smx[az][y] = mx;
    }
    __syncthreads();

    {   // exp + partial sums
        const int y = tid & 63, az = tid >> 6;
        const float mx = fmaxf(fmaxf(smx[0][y], smx[1][y]), fmaxf(smx[2][y], smx[3][y]));
        float s = 0.f;
        for (int a = az; a < 64; a += 4) {
            float e = __expf(att[a][y] - mx);
            att[a][y] = e;
            s += e;
        }
        ssm[az][y] = s;
    }
    __syncthreads();
    if (tid < 64)
        invL[tid] = 1.f / (ssm[0][tid] + ssm[1][tid] + ssm[2][tid] + ssm[3][tid]);
    __syncthreads();

    {   // aggregation; thread = (dp = d-pair, yb); y = yb + 16*it
        const int dp = tid & 15, yb = tid >> 4;
        #pragma unroll
        for (int it = 0; it < 4; ++it) {
            const int y = yb + it * 16;
            const unsigned short* rvr = rvT + (bh * 64 + y) * 2048 + dp * 2;
            float a0 = 0.f, a1 = 0.f;
            #pragma unroll 8
            for (int a = 0; a < 64; ++a) {
                unsigned int pk = *(const unsigned int*)(rvr + a * 32);
                float w = att[a][y];
                a0 = fmaf(w * lvL[a][2 * dp],     bf2f(pk),       a0);
                a1 = fmaf(w * lvL[a][2 * dp + 1], bf2f(pk >> 16), a1);
            }
            const float inv = invL[y];
            a0 *= inv; a1 *= inv;
            unsigned int st = f2bf(a0) | ((unsigned int)f2bf(a1) << 16);
            *(unsigned int*)(obuf + (((size_t)b * 64 + x) * 64 + y) * 256 + h * 32 + dp * 2) = st;
        }
    }
}

// ---------------------------------------------------------------------------
// XOR swizzle on 16B chunks (hs/ms tiles).
// ---------------------------------------------------------------------------
__device__ __forceinline__ int swz8(int r, int c, int rl) {
    return r * rl + ((((c >> 3) ^ (r & 7)) << 3) | (c & 7));
}

// ---------------------------------------------------------------------------
// Fused FFN tail, R13 (resubmit after infra flake): explicit load-batch /
// compute-batch K-loops. Model: 43us = 104K cy/block vs 4.4K cy MFMA,
// weights L2-resident (FETCH 8.8MB) -> exposed dependent-load latency. R2
// showed the compiler won't hoist (VGPR stuck at 76); R11's DMA chunks
// serialized on the barrier's vmcnt(0) drain. This version forces MLP in
// plain C: load ALL operand fragments for 4 consecutive K-steps into named
// register arrays BEFORE their MFMAs (compiler cannot sink a load past its
// first use -> 8-16 loads in flight per batch, one latency exposure per
// 4 K-steps). MFMA order stays kc-ascending -> bit-identical output.
// ---------------------------------------------------------------------------
__global__ __launch_bounds__(512, 2)
void ffn_fused(const unsigned short* __restrict__ A,
               const unsigned short* __restrict__ WoT,
               const unsigned short* __restrict__ W1T,
               const unsigned short* __restrict__ W2T,
               const float* __restrict__ xres,
               const float* __restrict__ g1, const float* __restrict__ be1,
               const float* __restrict__ b1, const float* __restrict__ b2,
               const float* __restrict__ g2, const float* __restrict__ be2,
               float* __restrict__ out)
{
    __shared__ unsigned short hs[32 * 256];   // h   32x256 bf16, swizzled (16KB)
    __shared__ unsigned short ms[32 * 512];   // mid 32x512 bf16, swizzled (32KB)
    __shared__ float ps[32][8], pq[32][8];
    const int lane = threadIdx.x & 63, wave = threadIdx.x >> 6;
    const int m0 = blockIdx.x * 32;
    const int lm = lane & 15, lk8 = (lane >> 4) * 8;
    const int rbase = (lane >> 4) * 4;
    const int col0 = wave * 32;               // phases 1/3: 32 cols per wave
    float hreg[2][2][4];                      // [row-tile][col-tile][r]

    // ---------- phase 1: h = LN(x + A @ WoT^T) ----------
    {
        f4 acc[2][2];
        #pragma unroll
        for (int i = 0; i < 2; ++i)
            #pragma unroll
            for (int j = 0; j < 2; ++j) acc[i][j] = (f4){0.f, 0.f, 0.f, 0.f};
        #pragma unroll
        for (int tc = 0; tc < 2; ++tc) {
            short8 af[4][2], bf[4][2];        // 16 x 16B = 64 VGPR batch
            #pragma unroll
            for (int u = 0; u < 4; ++u) {
                const int kc = (tc * 4 + u) * 32;
                #pragma unroll
                for (int i = 0; i < 2; ++i)
                    af[u][i] = *(const short8*)(A + (size_t)(m0 + i * 16 + lm) * 256 + kc + lk8);
                #pragma unroll
                for (int j = 0; j < 2; ++j)
                    bf[u][j] = *(const short8*)(WoT + (size_t)(col0 + j * 16 + lm) * 256 + kc + lk8);
            }
            #pragma unroll
            for (int u = 0; u < 4; ++u)
                #pragma unroll
                for (int i = 0; i < 2; ++i)
                    #pragma unroll
                    for (int j = 0; j < 2; ++j)
                        acc[i][j] = __builtin_amdgcn_mfma_f32_16x16x32_bf16(af[u][i], bf[u][j], acc[i][j], 0, 0, 0);
        }
        float v[2][2][4], s[2][4], q[2][4];
        #pragma unroll
        for (int i = 0; i < 2; ++i)
            #pragma unroll
            for (int r = 0; r < 4; ++r) { s[i][r] = 0.f; q[i][r] = 0.f; }
        #pragma unroll
        for (int i = 0; i < 2; ++i)
            #pragma unroll
            for (int j = 0; j < 2; ++j) {
                const int n = col0 + j * 16 + lm;
                #pragma unroll
                for (int r = 0; r < 4; ++r) {
                    const float t = acc[i][j][r] + xres[(size_t)(m0 + i * 16 + rbase + r) * 256 + n];
                    v[i][j][r] = t;
                    s[i][r] += t;
                    q[i][r] = fmaf(t, t, q[i][r]);
                }
            }
        #pragma unroll
        for (int off = 1; off < 16; off <<= 1)
            #pragma unroll
            for (int i = 0; i < 2; ++i)
                #pragma unroll
                for (int r = 0; r < 4; ++r) {
                    s[i][r] += __shfl_xor(s[i][r], off);
                    q[i][r] += __shfl_xor(q[i][r], off);
                }
        if (lm == 0)
            #pragma unroll
            for (int i = 0; i < 2; ++i)
                #pragma unroll
                for (int r = 0; r < 4; ++r) {
                    ps[i * 16 + rbase + r][wave] = s[i][r];
                    pq[i * 16 + rbase + r][wave] = q[i][r];
                }
        __syncthreads();
        #pragma unroll
        for (int i = 0; i < 2; ++i)
            #pragma unroll
            for (int r = 0; r < 4; ++r) {
                const int lr = i * 16 + rbase + r;
                const float Sm = ps[lr][0] + ps[lr][1] + ps[lr][2] + ps[lr][3]
                               + ps[lr][4] + ps[lr][5] + ps[lr][6] + ps[lr][7];
                const float Qm = pq[lr][0] + pq[lr][1] + pq[lr][2] + pq[lr][3]
                               + pq[lr][4] + pq[lr][5] + pq[lr][6] + pq[lr][7];
                const float mu = Sm * (1.f / 256.f);
                const float ri = rsqrtf(Qm * (1.f / 256.f) - mu * mu + 1e-5f);
                #pragma unroll
                for (int j = 0; j < 2; ++j) {
                    const int n = col0 + j * 16 + lm;
                    const unsigned short hb16 = f2bf((v[i][j][r] - mu) * ri * g1[n] + be1[n]);
                    hs[swz8(lr, n, 256)] = hb16;
                    hreg[i][j][r] = bf2f(hb16);
                }
            }
    }
    __syncthreads();

    // ---------- phase 2: mid = relu(h @ W1T^T + b1) ----------
    {
        const int c0 = wave * 64;
        f4 acc2[2][4];
        #pragma unroll
        for (int i = 0; i < 2; ++i)
            #pragma unroll
            for (int j = 0; j < 4; ++j) acc2[i][j] = (f4){0.f, 0.f, 0.f, 0.f};
        #pragma unroll
        for (int tc = 0; tc < 2; ++tc) {
            short8 bf[4][4];                  // 16 x 16B = 64 VGPR batch
            #pragma unroll
            for (int u = 0; u < 4; ++u) {
                const int kc = (tc * 4 + u) * 32;
                #pragma unroll
                for (int j = 0; j < 4; ++j)
                    bf[u][j] = *(const short8*)(W1T + (size_t)(c0 + j * 16 + lm) * 256 + kc + lk8);
            }
            #pragma unroll
            for (int u = 0; u < 4; ++u) {
                const int kc = (tc * 4 + u) * 32;
                short8 af[2];
                #pragma unroll
                for (int i = 0; i < 2; ++i)
                    af[i] = *(const short8*)(hs + swz8(i * 16 + lm, kc + lk8, 256));
                #pragma unroll
                for (int i = 0; i < 2; ++i)
                    #pragma unroll
                    for (int j = 0; j < 4; ++j)
                        acc2[i][j] = __builtin_amdgcn_mfma_f32_16x16x32_bf16(af[i], bf[u][j], acc2[i][j], 0, 0, 0);
            }
        }
        #pragma unroll
        for (int i = 0; i < 2; ++i)
            #pragma unroll
            for (int j = 0; j < 4; ++j) {
                const int n = c0 + j * 16 + lm;
                const float bb = b1[n];
                #pragma unroll
                for (int r = 0; r < 4; ++r)
                    ms[swz8(i * 16 + rbase + r, n, 512)] = f2bf(fmaxf(acc2[i][j][r] + bb, 0.f));
            }
    }
    __syncthreads();

    // ---------- phase 3: out = LN(h + mid @ W2T^T + b2) ----------
    {
        f4 acc[2][2];
        #pragma unroll
        for (int i = 0; i < 2; ++i)
            #pragma unroll
            for (int j = 0; j < 2; ++j) acc[i][j] = (f4){0.f, 0.f, 0.f, 0.f};
        #pragma unroll
        for (int tc = 0; tc < 4; ++tc) {
            short8 bf[4][2];                  // 8 x 16B = 32 VGPR batch
            #pragma unroll
            for (int u = 0; u < 4; ++u) {
                const int kc = (tc * 4 + u) * 32;
                #pragma unroll
                for (int j = 0; j < 2; ++j)
                    bf[u][j] = *(const short8*)(W2T + (size_t)(col0 + j * 16 + lm) * 512 + kc + lk8);
            }
            #pragma unroll
            for (int u = 0; u < 4; ++u) {
                const int kc = (tc * 4 + u) * 32;
                short8 af[2];
                #pragma unroll
                for (int i = 0; i < 2; ++i)
                    af[i] = *(const short8*)(ms + swz8(i * 16 + lm, kc + lk8, 512));
                #pragma unroll
                for (int i = 0; i < 2; ++i)
                    #pragma unroll
                    for (int j = 0; j < 2; ++j)
                        acc[i][j] = __builtin_amdgcn_mfma_f32_16x16x32_bf16(af[i], bf[u][j], acc[i][j], 0, 0, 0);
            }
        }
        float v[2][2][4], s[2][4], q[2][4];
        #pragma unroll
        for (int i = 0; i < 2; ++i)
            #pragma unroll
            for (int r = 0; r < 4; ++r) { s[i][r] = 0.f; q[i][r] = 0.f; }
        #pragma unroll
        for (int i = 0; i < 2; ++i)
            #pragma unroll
            for (int j = 0; j < 2; ++j) {
                const int n = col0 + j * 16 + lm;
                const float bb = b2[n];
                #pragma unroll
                for (int r = 0; r < 4; ++r) {
                    const float t = acc[i][j][r] + bb + hreg[i][j][r];
                    v[i][j][r] = t;
                    s[i][r] += t;
                    q[i][r] = fmaf(t, t, q[i][r]);
                }
            }
        #pragma unroll
        for (int off = 1; off < 16; off <<= 1)
            #pragma unroll
            for (int i = 0; i < 2; ++i)
                #pragma unroll
                for (int r = 0; r < 4; ++r) {
                    s[i][r] += __shfl_xor(s[i][r], off);
                    q[i][r] += __shfl_xor(q[i][r], off);
                }
        if (lm == 0)
            #pragma unroll
            for (int i = 0; i < 2; ++i)
                #pragma unroll
                for (int r = 0; r < 4; ++r) {
                    ps[i * 16 + rbase + r][wave] = s[i][r];
                    pq[i * 16 + rbase + r][wave] = q[i][r];
                }
        __syncthreads();
        #pragma unroll
        for (int i = 0; i < 2; ++i)
            #pragma unroll
            for (int r = 0; r < 4; ++r) {
                const int lr = i * 16 + rbase + r;
                const float Sm = ps[lr][0] + ps[lr][1] + ps[lr][2] + ps[lr][3]
                               + ps[lr][4] + ps[lr][5] + ps[lr][6] + ps[lr][7];
                const float Qm = pq[lr][0] + pq[lr][1] + pq[lr][2] + pq[lr][3]
                               + pq[lr][4] + pq[lr][5] + pq[lr][6] + pq[lr][7];
                const float mu = Sm * (1.f / 256.f);
                const float ri = rsqrtf(Qm * (1.f / 256.f) - mu * mu + 1e-5f);
                const int m = m0 + lr;
                #pragma unroll
                for (int j = 0; j < 2; ++j) {
                    const int n = col0 + j * 16 + lm;
                    out[(size_t)m * 256 + n] = (v[i][j][r] - mu) * ri * g2[n] + be2[n];
                }
            }
    }
}

// ---------------------------------------------------------------------------
extern "C" void kernel_launch(void* const* d_in, const int* in_sizes, int n_in,
                              void* d_out, int out_size, void* d_ws, size_t ws_size,
                              hipStream_t stream)
{
    const float* x    = (const float*)d_in[0];
    const float* Wlk  = (const float*)d_in[1];
    const float* Wrk  = (const float*)d_in[2];
    const float* Wlv  = (const float*)d_in[3];
    const float* Wrv  = (const float*)d_in[4];
    const float* Wout = (const float*)d_in[5];
    const float* g1   = (const float*)d_in[6];
    const float* be1  = (const float*)d_in[7];
    const float* W1   = (const float*)d_in[8];
    const float* b1   = (const float*)d_in[9];
    const float* W2   = (const float*)d_in[10];
    const float* b2   = (const float*)d_in[11];
    const float* g2   = (const float*)d_in[12];
    const float* be2  = (const float*)d_in[13];

    char* base = (char*)d_ws;
    const size_t MB = 1ull << 20;
    unsigned short* xb    = (unsigned short*)(base + 0);        // 4MB; reused as obuf
    unsigned short* obufb = (unsigned short*)(base + 0);
    unsigned short* projT = (unsigned short*)(base + 4 * MB);   // lkT,rkT,lvT,rvT 4x4MB
    unsigned short* lkT   = projT;
    unsigned short* rkT   = projT + 2097152;
    unsigned short* lvT   = projT + 2 * 2097152;
    unsigned short* rvT   = projT + 3 * 2097152;
    unsigned short* Sbuf  = (unsigned short*)(base + 32 * MB);  // 8MB bf16 scores
    unsigned short* WT    = (unsigned short*)(base + 40 * MB);  // 1.2MB

    // 1. casts (x -> bf16, weights -> transposed bf16)
    cast_all<<<2624, 256, 0, stream>>>(x, xb, Wlk, Wrk, Wlv, Wrv, Wout, W1, W2, WT);
    // 2. projections + head-major scatter (W strip LDS-staged)
    proj_mfma<<<dim3(16, 64), 256, 0, stream>>>(xb, WT, projT);
    // 3. scores via MFMA -> S (bf16)
    scores_mfma<<<256, 256, 0, stream>>>(lkT, rkT, Sbuf);
    // 4. softmax + aggregation -> obuf (bf16)
    softmax_agg<<<1024, 256, 0, stream>>>(Sbuf, lvT, rvT, obufb);
    // 5-7 fused: out = LN( h + relu(h@W1+b1)@W2 + b2 ),  h = LN(x + obuf@W_out)
    ffn_fused<<<256, 512, 0, stream>>>(obufb, WT + 262144, WT + 327680, WT + 458752,
                                       x, g1, be1, b1, b2, g2, be2, (float*)d_out);
}